// Round 13
// baseline (344.434 us; speedup 1.0000x reference)
//
#include <hip/hip_runtime.h>
#include <math.h>

#define NNODES 50000
#define NEDGES 800000
#define INDIM 256
#define HID 64
#define HEADS 4
#define OUTDIM 64
#define NEG_SLOPE 0.2f
#define NB ((NNODES + 1023) / 1024)   // 49 scan blocks

typedef __attribute__((ext_vector_type(4))) float f32x4;
typedef _Float16 __attribute__((ext_vector_type(8))) half8;

// ---------------- CSR build ----------------

__global__ __launch_bounds__(256) void hist_kernel(const int* __restrict__ dst,
                                                   int* __restrict__ deg) {
    int i = blockIdx.x * 256 + threadIdx.x;
    if (i < NEDGES) atomicAdd(&deg[dst[i]], 1);
}

__global__ __launch_bounds__(256) void bsum_kernel(const int* __restrict__ deg,
                                                   int* __restrict__ bsums) {
    int b = blockIdx.x, t = threadIdx.x;
    int base = b * 1024 + t * 4;
    int s = 0;
    #pragma unroll
    for (int e = 0; e < 4; ++e) { int i = base + e; if (i < NNODES) s += deg[i]; }
    #pragma unroll
    for (int o = 32; o; o >>= 1) s += __shfl_xor(s, o);
    __shared__ int ws[4];
    int lane = t & 63, wid = t >> 6;
    if (lane == 0) ws[wid] = s;
    __syncthreads();
    if (t == 0) bsums[b] = ws[0] + ws[1] + ws[2] + ws[3];
}

__global__ __launch_bounds__(256) void scan_write_kernel(const int* __restrict__ deg,
                                                         const int* __restrict__ bsums,
                                                         int* __restrict__ offs) {
    int b = blockIdx.x, t = threadIdx.x;
    int lane = t & 63, wid = t >> 6;
    int bv = (lane < b) ? bsums[lane] : 0;    // b <= NB-1 < 64
    #pragma unroll
    for (int o = 32; o; o >>= 1) bv += __shfl_xor(bv, o);  // block global offset
    int base = b * 1024 + t * 4;
    int v[4]; int tsum = 0;
    #pragma unroll
    for (int e = 0; e < 4; ++e) {
        int i = base + e;
        v[e] = (i < NNODES) ? deg[i] : 0;
        tsum += v[e];
    }
    int p = tsum;
    #pragma unroll
    for (int o = 1; o < 64; o <<= 1) { int u = __shfl_up(p, o); if (lane >= o) p += u; }
    __shared__ int ws[4];
    if (lane == 63) ws[wid] = p;
    __syncthreads();
    int woff = 0;
    for (int i = 0; i < wid; ++i) woff += ws[i];
    int run = bv + woff + p - tsum;           // exclusive prefix for this thread
    #pragma unroll
    for (int e = 0; e < 4; ++e) {
        int i = base + e;
        if (i < NNODES) { offs[i] = run; run += v[e]; }
    }
    if (b == 0 && t == 0) offs[NNODES] = NEDGES;
}

__global__ __launch_bounds__(256) void scatter_kernel(const int* __restrict__ src,
                                                      const int* __restrict__ dst,
                                                      const int* __restrict__ offs,
                                                      int* __restrict__ cursor,
                                                      int* __restrict__ ssorted) {
    int i = blockIdx.x * 256 + threadIdx.x;
    if (i < NEDGES) {
        int d = dst[i];
        int pos = offs[d] + atomicAdd(&cursor[d], 1);
        ssorted[pos] = src[i];
    }
}

// ---------------- weight transpose -> fp16 (both weights, one launch) ----

__global__ __launch_bounds__(256) void convert_wt_kernel(const float* __restrict__ W1,
                                                         _Float16* __restrict__ W1t,
                                                         const float* __restrict__ W2,
                                                         _Float16* __restrict__ W2t) {
    int idx = blockIdx.x * 256 + threadIdx.x;
    if (idx < 256 * 256) {
        int k = idx >> 8, n = idx & 255;
        W1t[n * 256 + k] = (_Float16)W1[idx];
    } else if (idx < 256 * 256 + 256 * 64) {
        int j = idx - 256 * 256;
        int k = j >> 6, n = j & 63;
        W2t[n * 256 + k] = (_Float16)W2[j];
    }
}

// ---------------- x -> fp16 streaming convert (coalesced, BW-bound) ------

__global__ __launch_bounds__(256) void convert_x_kernel(const float* __restrict__ x,
                                                        _Float16* __restrict__ xh) {
    int i = blockIdx.x * 256 + threadIdx.x;   // one half8 per thread
    if (i < NNODES * (INDIM / 8)) {
        const float4* xp = (const float4*)x;
        float4 f0 = xp[(size_t)i * 2];
        float4 f1 = xp[(size_t)i * 2 + 1];
        half8 v;
        v[0] = (_Float16)f0.x; v[1] = (_Float16)f0.y;
        v[2] = (_Float16)f0.z; v[3] = (_Float16)f0.w;
        v[4] = (_Float16)f1.x; v[5] = (_Float16)f1.y;
        v[6] = (_Float16)f1.z; v[7] = (_Float16)f1.w;
        ((half8*)xh)[i] = v;
    }
}

// ---------------- fp16 MFMA GEMM, LDS-free, BMx(BN) tile -----------------
// ELR=1 (BN=128): el/er NODE-MAJOR [M][4] for spmm1's one-line el gather.
// ELR=2 (BN=64): single head; per-wn partial dot + LDS combine.

template <int BM, int BN, bool AFP16, int ELR>
__global__ __launch_bounds__(256) void gemm_f16_kernel(
        const float* __restrict__ Af, const _Float16* __restrict__ Ah,
        const _Float16* __restrict__ Bt,
        _Float16* __restrict__ C,
        const float* __restrict__ al, const float* __restrict__ ar,
        float* __restrict__ el, float* __restrict__ er,
        int M, int N) {
    constexpr int K = 256;
    constexpr int NT = BN / 32;       // 16-wide n-tiles per wave
    constexpr int TM = BM / 32;       // 16-row tiles per wave
    int t = threadIdx.x;
    int lane = t & 63, w = t >> 6;
    int wm = w >> 1, wn = w & 1;
    int lr = lane & 15, quad = lane >> 4;
    int m0 = blockIdx.y * BM, n0 = blockIdx.x * BN;

    f32x4 acc[TM][NT];
    #pragma unroll
    for (int i = 0; i < TM; ++i)
        #pragma unroll
        for (int j = 0; j < NT; ++j) acc[i][j] = (f32x4){0.f, 0.f, 0.f, 0.f};

    int arow[TM];
    #pragma unroll
    for (int i = 0; i < TM; ++i) {
        int r = m0 + wm * (BM / 2) + i * 16 + lr;
        arow[i] = (r < M) ? r : (M - 1);
    }
    int brow[NT];
    #pragma unroll
    for (int j = 0; j < NT; ++j) brow[j] = n0 + wn * NT * 16 + j * 16 + lr;

    #pragma unroll
    for (int kk = 0; kk < K; kk += 32) {
        half8 a[TM], b[NT];
        if (AFP16) {
            #pragma unroll
            for (int i = 0; i < TM; ++i)
                a[i] = *(const half8*)(Ah + (size_t)arow[i] * K + kk + quad * 8);
        } else {
            #pragma unroll
            for (int i = 0; i < TM; ++i) {
                const float* ap = Af + (size_t)arow[i] * K + kk + quad * 8;
                float4 f0 = *(const float4*)ap;
                float4 f1 = *(const float4*)(ap + 4);
                a[i][0] = (_Float16)f0.x; a[i][1] = (_Float16)f0.y;
                a[i][2] = (_Float16)f0.z; a[i][3] = (_Float16)f0.w;
                a[i][4] = (_Float16)f1.x; a[i][5] = (_Float16)f1.y;
                a[i][6] = (_Float16)f1.z; a[i][7] = (_Float16)f1.w;
            }
        }
        #pragma unroll
        for (int j = 0; j < NT; ++j)
            b[j] = *(const half8*)(Bt + (size_t)brow[j] * K + kk + quad * 8);
        #pragma unroll
        for (int i = 0; i < TM; ++i)
            #pragma unroll
            for (int j = 0; j < NT; ++j)
                acc[i][j] = __builtin_amdgcn_mfma_f32_16x16x32_f16(a[i], b[j], acc[i][j], 0, 0, 0);
    }
    #pragma unroll
    for (int i = 0; i < TM; ++i) {
        #pragma unroll
        for (int r = 0; r < 4; ++r) {
            int row = m0 + wm * (BM / 2) + i * 16 + quad * 4 + r;
            if (row < M) {
                #pragma unroll
                for (int j = 0; j < NT; ++j)
                    C[(size_t)row * N + n0 + wn * NT * 16 + j * 16 + lr] =
                        (_Float16)acc[i][j][r];
            }
        }
    }
    if constexpr (ELR == 1) {
        int h = n0 / 64 + wn;
        float alh[NT], arh[NT];
        #pragma unroll
        for (int j = 0; j < NT; ++j) {
            alh[j] = al[h * 64 + j * 16 + lr];
            arh[j] = ar[h * 64 + j * 16 + lr];
        }
        #pragma unroll
        for (int i = 0; i < TM; ++i) {
            #pragma unroll
            for (int r = 0; r < 4; ++r) {
                float pel = 0.f, per = 0.f;
                #pragma unroll
                for (int j = 0; j < NT; ++j) {
                    pel = fmaf(acc[i][j][r], alh[j], pel);
                    per = fmaf(acc[i][j][r], arh[j], per);
                }
                #pragma unroll
                for (int o = 1; o < 16; o <<= 1) {
                    pel += __shfl_xor(pel, o);
                    per += __shfl_xor(per, o);
                }
                if (lr == 0) {
                    int row = m0 + wm * (BM / 2) + i * 16 + quad * 4 + r;
                    if (row < M) {
                        el[(size_t)row * 4 + h] = pel;   // node-major [M][4]
                        er[(size_t)row * 4 + h] = per;
                    }
                }
            }
        }
    }
    if constexpr (ELR == 2) {
        __shared__ float elbuf[BM], erbuf[BM];
        float alv[NT], arv[NT];
        #pragma unroll
        for (int j = 0; j < NT; ++j) {
            alv[j] = al[wn * NT * 16 + j * 16 + lr];
            arv[j] = ar[wn * NT * 16 + j * 16 + lr];
        }
        float pel_s[TM][4], per_s[TM][4];
        #pragma unroll
        for (int i = 0; i < TM; ++i) {
            #pragma unroll
            for (int r = 0; r < 4; ++r) {
                float pel = 0.f, per = 0.f;
                #pragma unroll
                for (int j = 0; j < NT; ++j) {
                    pel = fmaf(acc[i][j][r], alv[j], pel);
                    per = fmaf(acc[i][j][r], arv[j], per);
                }
                #pragma unroll
                for (int o = 1; o < 16; o <<= 1) {
                    pel += __shfl_xor(pel, o);
                    per += __shfl_xor(per, o);
                }
                pel_s[i][r] = pel; per_s[i][r] = per;
            }
        }
        if (wn == 1 && lr == 0) {
            #pragma unroll
            for (int i = 0; i < TM; ++i)
                #pragma unroll
                for (int r = 0; r < 4; ++r) {
                    int rl = wm * (BM / 2) + i * 16 + quad * 4 + r;
                    elbuf[rl] = pel_s[i][r];
                    erbuf[rl] = per_s[i][r];
                }
        }
        __syncthreads();
        if (wn == 0 && lr == 0) {
            #pragma unroll
            for (int i = 0; i < TM; ++i)
                #pragma unroll
                for (int r = 0; r < 4; ++r) {
                    int rl = wm * (BM / 2) + i * 16 + quad * 4 + r;
                    int row = m0 + rl;
                    if (row < M) {
                        el[row] = pel_s[i][r] + elbuf[rl];
                        er[row] = per_s[i][r] + erbuf[rl];
                    }
                }
        }
    }
}

// ---------------- fused softmax + weighted aggregation (layer 1) ----------
// R24: depth-3 rotation. R23 budget: lifetime 16.5k cy = 8 slots x ~2k;
// depth-2 steady state is ~L/2 per slot with L~4k loaded. Depth-3 (el/fv
// issued 2 iterations before consume, sj 4 ahead) -> ~L/3 per slot.
// +1 (el,fv,sj) set = +6-7 VGPR (~36 total; R13 ran 32 @ 80% occ).

__global__ __launch_bounds__(256) void spmm1_kernel(const _Float16* __restrict__ feat,  // [N][256]
                                                    const float* __restrict__ el,  // [N][4]
                                                    const float* __restrict__ er,  // [N][4]
                                                    const int* __restrict__ offs,
                                                    const int* __restrict__ ssorted,
                                                    _Float16* __restrict__ h1) {
    int n = blockIdx.x * 4 + (threadIdx.x >> 6);   // wave = node, all 4 heads
    if (n >= NNODES) return;
    int l = threadIdx.x & 63;
    int p2 = l >> 5;              // edge-pair half (2 edges per VMEM)
    int q  = l & 31;              // 32 lanes cover 512B = 4 heads x 64 dims
    int h  = q >> 3;              // this lane's head
    int start = offs[n], end = offs[n + 1];
    int nst = (end - start + 1) >> 1;   // 2-edge slots
    float ern = er[(size_t)n * 4 + h];
    const half8* f8 = (const half8*)feat;   // node stride 32 half8
    float acc[8];
    #pragma unroll
    for (int i = 0; i < 8; ++i) acc[i] = 0.f;
    float ws = 0.f;
    half8 z;
    #pragma unroll
    for (int i = 0; i < 8; ++i) z[i] = (_Float16)0;
    int sjX = 0, sjY = 0, sjN = 0;
    float elA = 0.f, elB = 0.f, elC = 0.f;
    half8 fvA = z, fvB = z, fvC = z;
    if (nst > 0) {                 // prologue: sj slots 0..3; el/fv slots 0,1
        int x0 = start + p2;
        int s0 = ssorted[x0 < end ? x0 : start];
        int s1 = 0;
        if (nst > 1) { int x1 = start + 2 + p2; s1 = ssorted[x1 < end ? x1 : start]; }
        if (nst > 2) { int x2 = start + 4 + p2; sjX = ssorted[x2 < end ? x2 : start]; }
        if (nst > 3) { int x3 = start + 6 + p2; sjY = ssorted[x3 < end ? x3 : start]; }
        elA = el[(size_t)s0 * 4 + h];
        fvA = f8[(size_t)s0 * 32 + q];
        if (nst > 1) {
            elB = el[(size_t)s1 * 4 + h];
            fvB = f8[(size_t)s1 * 32 + q];
        }
    }
    for (int js = 0; js < nst; ++js) {
        if (js + 2 < nst) {        // issue slot j+2's el/feat (sjX ready)
            elC = el[(size_t)sjX * 4 + h];
            fvC = f8[(size_t)sjX * 32 + q];
        }
        if (js + 4 < nst) {        // issue slot j+4's sj
            int x = start + (js + 4) * 2 + p2;
            sjN = ssorted[x < end ? x : start];
        }
        // consume slot js (A regs; loads issued two iterations ago)
        bool vld = (start + js * 2 + p2) < end;
        float ev = elA + ern;
        ev = ev > 0.f ? ev : NEG_SLOPE * ev;
        float w = vld ? __expf(ev) : 0.f;    // no max-sub (safe: |e|<~8)
        ws += w;
        #pragma unroll
        for (int i = 0; i < 8; ++i) acc[i] = fmaf(w, (float)fvA[i], acc[i]);
        elA = elB; fvA = fvB;                // rotate depth-3
        elB = elC; fvB = fvC;
        sjX = sjY; sjY = sjN;
    }
    // fold the two edge-pair halves
    ws += __shfl_xor(ws, 32);
    #pragma unroll
    for (int i = 0; i < 8; ++i) acc[i] += __shfl_xor(acc[i], 32);
    if (l < 32) {
        float inv = ws > 0.f ? 1.f / ws : 0.f;
        half8 hv;
        #pragma unroll
        for (int i = 0; i < 8; ++i) {
            float v = acc[i] * inv;
            v = v > 0.f ? v : __expf(v) - 1.f;   // ELU
            hv[i] = (_Float16)v;
        }
        *(half8*)&h1[(size_t)n * 256 + q * 8] = hv;    // 512B/node contiguous
    }
}

// ---------------- fused softmax + weighted aggregation (layer 2) ----------
// Single head, 64 dims, fp32 out. Same depth-3 rotation (slots of 8 edges;
// nst ~ 2 so expectation ~0 here, applied for symmetry).

__global__ __launch_bounds__(256) void spmm2_kernel(const _Float16* __restrict__ feat,
                                                    const float* __restrict__ el,
                                                    const float* __restrict__ er,
                                                    const int* __restrict__ offs,
                                                    const int* __restrict__ ssorted,
                                                    float* __restrict__ out) {
    int n = blockIdx.x * 4 + (threadIdx.x >> 6);
    if (n >= NNODES) return;
    int l = threadIdx.x & 63;
    int e8 = l >> 3, li = l & 7;
    int start = offs[n], end = offs[n + 1];
    int nst = (end - start + 7) >> 3;   // 8-edge slots
    float ern = er[n];
    const half8* f8 = (const half8*)feat;   // node stride 8 half8s
    float acc[8];
    #pragma unroll
    for (int i = 0; i < 8; ++i) acc[i] = 0.f;
    float ws = 0.f;
    half8 z;
    #pragma unroll
    for (int i = 0; i < 8; ++i) z[i] = (_Float16)0;
    int sjX = 0, sjY = 0, sjN = 0;
    float elA = 0.f, elB = 0.f, elC = 0.f;
    half8 fvA = z, fvB = z, fvC = z;
    if (nst > 0) {
        int x0 = start + e8;
        int s0 = ssorted[x0 < end ? x0 : start];
        int s1 = 0;
        if (nst > 1) { int x1 = start + 8 + e8; s1 = ssorted[x1 < end ? x1 : start]; }
        if (nst > 2) { int x2 = start + 16 + e8; sjX = ssorted[x2 < end ? x2 : start]; }
        if (nst > 3) { int x3 = start + 24 + e8; sjY = ssorted[x3 < end ? x3 : start]; }
        elA = el[s0];
        fvA = f8[(size_t)s0 * 8 + li];
        if (nst > 1) {
            elB = el[s1];
            fvB = f8[(size_t)s1 * 8 + li];
        }
    }
    for (int js = 0; js < nst; ++js) {
        if (js + 2 < nst) {
            elC = el[sjX];
            fvC = f8[(size_t)sjX * 8 + li];
        }
        if (js + 4 < nst) {
            int x = start + (js + 4) * 8 + e8;
            sjN = ssorted[x < end ? x : start];
        }
        bool vld = (start + js * 8 + e8) < end;
        float ev = elA + ern;
        ev = ev > 0.f ? ev : NEG_SLOPE * ev;
        float w = vld ? __expf(ev) : 0.f;
        ws += w;
        #pragma unroll
        for (int i = 0; i < 8; ++i) acc[i] = fmaf(w, (float)fvA[i], acc[i]);
        elA = elB; fvA = fvB;
        elB = elC; fvB = fvC;
        sjX = sjY; sjY = sjN;
    }
    #pragma unroll
    for (int o = 8; o < 64; o <<= 1) {
        ws += __shfl_xor(ws, o);
        #pragma unroll
        for (int i = 0; i < 8; ++i) acc[i] += __shfl_xor(acc[i], o);
    }
    if (e8 == 0) {
        float inv = ws > 0.f ? 1.f / ws : 0.f;
        float4 o0, o1;
        o0.x = acc[0] * inv; o0.y = acc[1] * inv;
        o0.z = acc[2] * inv; o0.w = acc[3] * inv;
        o1.x = acc[4] * inv; o1.y = acc[5] * inv;
        o1.z = acc[6] * inv; o1.w = acc[7] * inv;
        float4* op = (float4*)(out + (size_t)n * 64 + li * 8);
        op[0] = o0; op[1] = o1;
    }
}

// ---------------- launch ----------------

extern "C" void kernel_launch(void* const* d_in, const int* in_sizes, int n_in,
                              void* d_out, int out_size, void* d_ws, size_t ws_size,
                              hipStream_t stream) {
    const float* x   = (const float*)d_in[0];
    const int*   src = (const int*)d_in[1];
    const int*   dst = (const int*)d_in[2];
    const float* W1  = (const float*)d_in[3];
    const float* al1 = (const float*)d_in[4];
    const float* ar1 = (const float*)d_in[5];
    const float* W2  = (const float*)d_in[6];
    const float* al2 = (const float*)d_in[7];
    const float* ar2 = (const float*)d_in[8];
    float* out = (float*)d_out;

    char* ws = (char*)d_ws;
    size_t off = 0;
    auto alloc = [&](size_t bytes) -> void* {
        void* p = ws + off;
        off += (bytes + 255) & ~(size_t)255;
        return p;
    };
    _Float16* feat1 = (_Float16*)alloc((size_t)NNODES * 256 * 2);   // node-major [N][256]
    _Float16* h1    = (_Float16*)alloc((size_t)NNODES * 256 * 2);   // node-major [N][256]
    _Float16* W1t   = (_Float16*)alloc((size_t)256 * 256 * 2);
    _Float16* W2t   = (_Float16*)alloc((size_t)64 * 256 * 2);
    float* el1    = (float*)alloc((size_t)NNODES * 4 * 4);          // node-major [N][4]
    float* er1    = (float*)alloc((size_t)NNODES * 4 * 4);
    float* el2    = (float*)alloc((size_t)NNODES * 4);
    float* er2    = (float*)alloc((size_t)NNODES * 4);
    int* deg      = (int*)alloc((size_t)NNODES * 4);
    int* cursor   = (int*)alloc((size_t)NNODES * 4);
    int* offs     = (int*)alloc((size_t)(NNODES + 1) * 4);
    int* bsums    = (int*)alloc((size_t)NB * 4);
    int* ssorted  = (int*)alloc((size_t)NEDGES * 4);
    _Float16* feat2 = feat1;   // feat1 dead after spmm1; reuse for layer 2
    _Float16* xh = h1;         // x-fp16 staging; dead before spmm1 writes h1

    // --- CSR build ---
    hipMemsetAsync(deg, 0, (size_t)NNODES * 4, stream);
    hipMemsetAsync(cursor, 0, (size_t)NNODES * 4, stream);
    hist_kernel<<<(NEDGES + 255) / 256, 256, 0, stream>>>(dst, deg);
    bsum_kernel<<<NB, 256, 0, stream>>>(deg, bsums);
    scan_write_kernel<<<NB, 256, 0, stream>>>(deg, bsums, offs);
    scatter_kernel<<<(NEDGES + 255) / 256, 256, 0, stream>>>(src, dst, offs, cursor, ssorted);

    // --- weight + x conversions ---
    convert_wt_kernel<<<(256 * 256 + 256 * 64 + 255) / 256, 256, 0, stream>>>(
        W1, W1t, W2, W2t);
    convert_x_kernel<<<(NNODES * (INDIM / 8) + 255) / 256, 256, 0, stream>>>(x, xh);

    // --- Layer 1: BM=64 fp16 GEMM (node-major el/er); depth-3 SpMM ---
    gemm_f16_kernel<64, 128, true, 1><<<dim3(256 / 128, (NNODES + 63) / 64), 256, 0, stream>>>(
        nullptr, xh, W1t, feat1, al1, ar1, el1, er1, NNODES, 256);
    spmm1_kernel<<<(NNODES + 3) / 4, 256, 0, stream>>>(
        feat1, el1, er1, offs, ssorted, h1);

    // --- Layer 2: BM=64 fp16 GEMM + fused el/er; depth-3 SpMM ---
    gemm_f16_kernel<64, 64, true, 2><<<dim3(64 / 64, (NNODES + 63) / 64), 256, 0, stream>>>(
        nullptr, h1, W2t, feat2, al2, ar2, el2, er2, NNODES, 64);
    spmm2_kernel<<<(NNODES + 3) / 4, 256, 0, stream>>>(
        feat2, el2, er2, offs, ssorted, out);
}

// Round 14
// 316.520 us; speedup vs baseline: 1.0882x; 1.0882x over previous
//
#include <hip/hip_runtime.h>
#include <math.h>

#define NNODES 50000
#define NEDGES 800000
#define INDIM 256
#define HID 64
#define HEADS 4
#define OUTDIM 64
#define NEG_SLOPE 0.2f
#define NB ((NNODES + 1023) / 1024)   // 49 scan blocks
#define HB ((NEDGES + 255) / 256)     // 3125 hist blocks
#define XB ((NNODES * (INDIM / 8) + 255) / 256)   // 6250 convert_x blocks
#define WB ((256 * 256 + 256 * 64 + 255) / 256)   // 320 convert_wt blocks

typedef __attribute__((ext_vector_type(4))) float f32x4;
typedef _Float16 __attribute__((ext_vector_type(8))) half8;

// ---------------- CSR build (bsum/scan stay standalone) ----------------

__global__ __launch_bounds__(256) void bsum_kernel(const int* __restrict__ deg,
                                                   int* __restrict__ bsums) {
    int b = blockIdx.x, t = threadIdx.x;
    int base = b * 1024 + t * 4;
    int s = 0;
    #pragma unroll
    for (int e = 0; e < 4; ++e) { int i = base + e; if (i < NNODES) s += deg[i]; }
    #pragma unroll
    for (int o = 32; o; o >>= 1) s += __shfl_xor(s, o);
    __shared__ int ws[4];
    int lane = t & 63, wid = t >> 6;
    if (lane == 0) ws[wid] = s;
    __syncthreads();
    if (t == 0) bsums[b] = ws[0] + ws[1] + ws[2] + ws[3];
}

__global__ __launch_bounds__(256) void scan_write_kernel(const int* __restrict__ deg,
                                                         const int* __restrict__ bsums,
                                                         int* __restrict__ offs) {
    int b = blockIdx.x, t = threadIdx.x;
    int lane = t & 63, wid = t >> 6;
    int bv = (lane < b) ? bsums[lane] : 0;    // b <= NB-1 < 64
    #pragma unroll
    for (int o = 32; o; o >>= 1) bv += __shfl_xor(bv, o);  // block global offset
    int base = b * 1024 + t * 4;
    int v[4]; int tsum = 0;
    #pragma unroll
    for (int e = 0; e < 4; ++e) {
        int i = base + e;
        v[e] = (i < NNODES) ? deg[i] : 0;
        tsum += v[e];
    }
    int p = tsum;
    #pragma unroll
    for (int o = 1; o < 64; o <<= 1) { int u = __shfl_up(p, o); if (lane >= o) p += u; }
    __shared__ int ws[4];
    if (lane == 63) ws[wid] = p;
    __syncthreads();
    int woff = 0;
    for (int i = 0; i < wid; ++i) woff += ws[i];
    int run = bv + woff + p - tsum;           // exclusive prefix for this thread
    #pragma unroll
    for (int e = 0; e < 4; ++e) {
        int i = base + e;
        if (i < NNODES) { offs[i] = run; run += v[e]; }
    }
    if (b == 0 && t == 0) offs[NNODES] = NEDGES;
}

// ---------------- fused prep: hist + convert_wt + convert_x ----------------
// R25: hist, W->fp16 transpose, x->fp16 are mutually independent; one
// grid-partitioned launch overlaps hist's atomic latency with the
// BW-bound converts and drops 2 launch gaps.

__global__ __launch_bounds__(256) void prep_kernel(const int* __restrict__ dst,
                                                   int* __restrict__ deg,
                                                   const float* __restrict__ W1,
                                                   _Float16* __restrict__ W1t,
                                                   const float* __restrict__ W2,
                                                   _Float16* __restrict__ W2t,
                                                   const float* __restrict__ x,
                                                   _Float16* __restrict__ xh) {
    int b = blockIdx.x;
    if (b < HB) {                         // histogram
        int i = b * 256 + threadIdx.x;
        if (i < NEDGES) atomicAdd(&deg[dst[i]], 1);
    } else if (b < HB + XB) {             // x -> fp16 (one half8/thread)
        int i = (b - HB) * 256 + threadIdx.x;
        if (i < NNODES * (INDIM / 8)) {
            const float4* xp = (const float4*)x;
            float4 f0 = xp[(size_t)i * 2];
            float4 f1 = xp[(size_t)i * 2 + 1];
            half8 v;
            v[0] = (_Float16)f0.x; v[1] = (_Float16)f0.y;
            v[2] = (_Float16)f0.z; v[3] = (_Float16)f0.w;
            v[4] = (_Float16)f1.x; v[5] = (_Float16)f1.y;
            v[6] = (_Float16)f1.z; v[7] = (_Float16)f1.w;
            ((half8*)xh)[i] = v;
        }
    } else {                              // weight transpose -> fp16
        int idx = (b - HB - XB) * 256 + threadIdx.x;
        if (idx < 256 * 256) {
            int k = idx >> 8, n = idx & 255;
            W1t[n * 256 + k] = (_Float16)W1[idx];
        } else if (idx < 256 * 256 + 256 * 64) {
            int j = idx - 256 * 256;
            int k = j >> 6, n = j & 63;
            W2t[n * 256 + k] = (_Float16)W2[j];
        }
    }
}

// ---------------- fp16 MFMA GEMM body (shared by fused + standalone) -----
// ELR=1 (BN=128): el/er NODE-MAJOR [M][4] for spmm1's one-line el gather.
// ELR=2 (BN=64): single head; per-wn partial dot + LDS combine.

template <int BM, int BN, int ELR>
__device__ __forceinline__ void gemm_body(
        const _Float16* __restrict__ Ah,
        const _Float16* __restrict__ Bt,
        _Float16* __restrict__ C,
        const float* __restrict__ al, const float* __restrict__ ar,
        float* __restrict__ el, float* __restrict__ er,
        int M, int N, int m0, int n0) {
    constexpr int K = 256;
    constexpr int NT = BN / 32;       // 16-wide n-tiles per wave
    constexpr int TM = BM / 32;       // 16-row tiles per wave
    int t = threadIdx.x;
    int lane = t & 63, w = t >> 6;
    int wm = w >> 1, wn = w & 1;
    int lr = lane & 15, quad = lane >> 4;

    f32x4 acc[TM][NT];
    #pragma unroll
    for (int i = 0; i < TM; ++i)
        #pragma unroll
        for (int j = 0; j < NT; ++j) acc[i][j] = (f32x4){0.f, 0.f, 0.f, 0.f};

    int arow[TM];
    #pragma unroll
    for (int i = 0; i < TM; ++i) {
        int r = m0 + wm * (BM / 2) + i * 16 + lr;
        arow[i] = (r < M) ? r : (M - 1);
    }
    int brow[NT];
    #pragma unroll
    for (int j = 0; j < NT; ++j) brow[j] = n0 + wn * NT * 16 + j * 16 + lr;

    #pragma unroll
    for (int kk = 0; kk < K; kk += 32) {
        half8 a[TM], b[NT];
        #pragma unroll
        for (int i = 0; i < TM; ++i)
            a[i] = *(const half8*)(Ah + (size_t)arow[i] * K + kk + quad * 8);
        #pragma unroll
        for (int j = 0; j < NT; ++j)
            b[j] = *(const half8*)(Bt + (size_t)brow[j] * K + kk + quad * 8);
        #pragma unroll
        for (int i = 0; i < TM; ++i)
            #pragma unroll
            for (int j = 0; j < NT; ++j)
                acc[i][j] = __builtin_amdgcn_mfma_f32_16x16x32_f16(a[i], b[j], acc[i][j], 0, 0, 0);
    }
    #pragma unroll
    for (int i = 0; i < TM; ++i) {
        #pragma unroll
        for (int r = 0; r < 4; ++r) {
            int row = m0 + wm * (BM / 2) + i * 16 + quad * 4 + r;
            if (row < M) {
                #pragma unroll
                for (int j = 0; j < NT; ++j)
                    C[(size_t)row * N + n0 + wn * NT * 16 + j * 16 + lr] =
                        (_Float16)acc[i][j][r];
            }
        }
    }
    if constexpr (ELR == 1) {
        int h = n0 / 64 + wn;
        float alh[NT], arh[NT];
        #pragma unroll
        for (int j = 0; j < NT; ++j) {
            alh[j] = al[h * 64 + j * 16 + lr];
            arh[j] = ar[h * 64 + j * 16 + lr];
        }
        #pragma unroll
        for (int i = 0; i < TM; ++i) {
            #pragma unroll
            for (int r = 0; r < 4; ++r) {
                float pel = 0.f, per = 0.f;
                #pragma unroll
                for (int j = 0; j < NT; ++j) {
                    pel = fmaf(acc[i][j][r], alh[j], pel);
                    per = fmaf(acc[i][j][r], arh[j], per);
                }
                #pragma unroll
                for (int o = 1; o < 16; o <<= 1) {
                    pel += __shfl_xor(pel, o);
                    per += __shfl_xor(per, o);
                }
                if (lr == 0) {
                    int row = m0 + wm * (BM / 2) + i * 16 + quad * 4 + r;
                    if (row < M) {
                        el[(size_t)row * 4 + h] = pel;   // node-major [M][4]
                        er[(size_t)row * 4 + h] = per;
                    }
                }
            }
        }
    }
    if constexpr (ELR == 2) {
        __shared__ float elbuf[BM], erbuf[BM];
        float alv[NT], arv[NT];
        #pragma unroll
        for (int j = 0; j < NT; ++j) {
            alv[j] = al[wn * NT * 16 + j * 16 + lr];
            arv[j] = ar[wn * NT * 16 + j * 16 + lr];
        }
        float pel_s[TM][4], per_s[TM][4];
        #pragma unroll
        for (int i = 0; i < TM; ++i) {
            #pragma unroll
            for (int r = 0; r < 4; ++r) {
                float pel = 0.f, per = 0.f;
                #pragma unroll
                for (int j = 0; j < NT; ++j) {
                    pel = fmaf(acc[i][j][r], alv[j], pel);
                    per = fmaf(acc[i][j][r], arv[j], per);
                }
                #pragma unroll
                for (int o = 1; o < 16; o <<= 1) {
                    pel += __shfl_xor(pel, o);
                    per += __shfl_xor(per, o);
                }
                pel_s[i][r] = pel; per_s[i][r] = per;
            }
        }
        if (wn == 1 && lr == 0) {
            #pragma unroll
            for (int i = 0; i < TM; ++i)
                #pragma unroll
                for (int r = 0; r < 4; ++r) {
                    int rl = wm * (BM / 2) + i * 16 + quad * 4 + r;
                    elbuf[rl] = pel_s[i][r];
                    erbuf[rl] = per_s[i][r];
                }
        }
        __syncthreads();
        if (wn == 0 && lr == 0) {
            #pragma unroll
            for (int i = 0; i < TM; ++i)
                #pragma unroll
                for (int r = 0; r < 4; ++r) {
                    int rl = wm * (BM / 2) + i * 16 + quad * 4 + r;
                    int row = m0 + rl;
                    if (row < M) {
                        el[row] = pel_s[i][r] + elbuf[rl];
                        er[row] = per_s[i][r] + erbuf[rl];
                    }
                }
        }
    }
}

// ---------------- fused gemm1 + scatter ----------------------------------
// R25: gemm1 (feature chain) and scatter (CSR chain) are independent;
// gemm blocks first (MFMA-dense fills CUs), scatter's atomic/random-write
// latency overlaps behind. 1564 gemm blocks (BM=64: mt=bid>>1, nt=bid&1)
// + 3125 scatter blocks.

__global__ __launch_bounds__(256) void gemm1_scatter_kernel(
        const _Float16* __restrict__ Ah, const _Float16* __restrict__ Bt,
        _Float16* __restrict__ C,
        const float* __restrict__ al, const float* __restrict__ ar,
        float* __restrict__ el, float* __restrict__ er,
        int gemmBlocks,
        const int* __restrict__ src, const int* __restrict__ dst,
        const int* __restrict__ offs, int* __restrict__ cursor,
        int* __restrict__ ssorted) {
    int b = blockIdx.x;
    if (b < gemmBlocks) {
        int m0 = (b >> 1) * 64, n0 = (b & 1) * 128;
        gemm_body<64, 128, 1>(Ah, Bt, C, al, ar, el, er, NNODES, 256, m0, n0);
    } else {
        int i = (b - gemmBlocks) * 256 + threadIdx.x;
        if (i < NEDGES) {
            int d = dst[i];
            int pos = offs[d] + atomicAdd(&cursor[d], 1);
            ssorted[pos] = src[i];
        }
    }
}

// ---------------- standalone gemm (layer 2) ------------------------------

template <int BM, int BN, int ELR>
__global__ __launch_bounds__(256) void gemm_f16_kernel(
        const _Float16* __restrict__ Ah, const _Float16* __restrict__ Bt,
        _Float16* __restrict__ C,
        const float* __restrict__ al, const float* __restrict__ ar,
        float* __restrict__ el, float* __restrict__ er,
        int M, int N) {
    int m0 = blockIdx.y * BM, n0 = blockIdx.x * BN;
    gemm_body<BM, BN, ELR>(Ah, Bt, C, al, ar, el, er, M, N, m0, n0);
}

// ---------------- fused softmax + weighted aggregation (layer 1) ----------
// R22 winner (reverted from null depth-3): depth-2 software pipeline;
// wave = node, all 4 heads; 2 edges per VMEM; consume slot j while slot
// j+1's el/feat and slot j+2's ssorted are in flight. 24 VGPR, occ 66%.
// R24 verdict: 63.5us is the L2-miss random-service floor (~3.6 TB/s,
// 200MB fetch) - deeper pipelining is null.

__global__ __launch_bounds__(256) void spmm1_kernel(const _Float16* __restrict__ feat,  // [N][256]
                                                    const float* __restrict__ el,  // [N][4]
                                                    const float* __restrict__ er,  // [N][4]
                                                    const int* __restrict__ offs,
                                                    const int* __restrict__ ssorted,
                                                    _Float16* __restrict__ h1) {
    int n = blockIdx.x * 4 + (threadIdx.x >> 6);   // wave = node, all 4 heads
    if (n >= NNODES) return;
    int l = threadIdx.x & 63;
    int p2 = l >> 5;              // edge-pair half (2 edges per VMEM)
    int q  = l & 31;              // 32 lanes cover 512B = 4 heads x 64 dims
    int h  = q >> 3;              // this lane's head
    int start = offs[n], end = offs[n + 1];
    int nst = (end - start + 1) >> 1;   // 2-edge slots
    float ern = er[(size_t)n * 4 + h];
    const half8* f8 = (const half8*)feat;   // node stride 32 half8
    float acc[8];
    #pragma unroll
    for (int i = 0; i < 8; ++i) acc[i] = 0.f;
    float ws = 0.f;
    half8 z;
    #pragma unroll
    for (int i = 0; i < 8; ++i) z[i] = (_Float16)0;
    int sjB = 0, sjN = 0;
    float elA = 0.f, elB = 0.f;
    half8 fvA = z, fvB = z;
    if (nst > 0) {                 // prologue: slot0 chain + slot1 sj in flight
        int x0 = start + p2;
        int sjA = ssorted[x0 < end ? x0 : start];
        if (nst > 1) {
            int x1 = start + 2 + p2;
            sjB = ssorted[x1 < end ? x1 : start];
        }
        elA = el[(size_t)sjA * 4 + h];
        fvA = f8[(size_t)sjA * 32 + q];
    }
    for (int js = 0; js < nst; ++js) {
        if (js + 1 < nst) {        // issue next slot's el/feat (sj ready)
            elB = el[(size_t)sjB * 4 + h];
            fvB = f8[(size_t)sjB * 32 + q];
        }
        if (js + 2 < nst) {        // issue next-next slot's sj
            int x = start + (js + 2) * 2 + p2;
            sjN = ssorted[x < end ? x : start];
        }
        // consume slot js (A regs; waits only on loads issued last iteration)
        bool vld = (start + js * 2 + p2) < end;
        float ev = elA + ern;
        ev = ev > 0.f ? ev : NEG_SLOPE * ev;
        float w = vld ? __expf(ev) : 0.f;    // no max-sub (safe: |e|<~8)
        ws += w;
        #pragma unroll
        for (int i = 0; i < 8; ++i) acc[i] = fmaf(w, (float)fvA[i], acc[i]);
        elA = elB; fvA = fvB; sjB = sjN;     // rotate
    }
    // fold the two edge-pair halves
    ws += __shfl_xor(ws, 32);
    #pragma unroll
    for (int i = 0; i < 8; ++i) acc[i] += __shfl_xor(acc[i], 32);
    if (l < 32) {
        float inv = ws > 0.f ? 1.f / ws : 0.f;
        half8 hv;
        #pragma unroll
        for (int i = 0; i < 8; ++i) {
            float v = acc[i] * inv;
            v = v > 0.f ? v : __expf(v) - 1.f;   // ELU
            hv[i] = (_Float16)v;
        }
        *(half8*)&h1[(size_t)n * 256 + q * 8] = hv;    // 512B/node contiguous
    }
}

// ---------------- fused softmax + weighted aggregation (layer 2) ----------
// Single head, 64 dims, fp32 out. Depth-2 rotation (slots of 8 edges).

__global__ __launch_bounds__(256) void spmm2_kernel(const _Float16* __restrict__ feat,
                                                    const float* __restrict__ el,
                                                    const float* __restrict__ er,
                                                    const int* __restrict__ offs,
                                                    const int* __restrict__ ssorted,
                                                    float* __restrict__ out) {
    int n = blockIdx.x * 4 + (threadIdx.x >> 6);
    if (n >= NNODES) return;
    int l = threadIdx.x & 63;
    int e8 = l >> 3, li = l & 7;
    int start = offs[n], end = offs[n + 1];
    int nst = (end - start + 7) >> 3;   // 8-edge slots
    float ern = er[n];
    const half8* f8 = (const half8*)feat;   // node stride 8 half8s
    float acc[8];
    #pragma unroll
    for (int i = 0; i < 8; ++i) acc[i] = 0.f;
    float ws = 0.f;
    half8 z;
    #pragma unroll
    for (int i = 0; i < 8; ++i) z[i] = (_Float16)0;
    int sjB = 0, sjN = 0;
    float elA = 0.f, elB = 0.f;
    half8 fvA = z, fvB = z;
    if (nst > 0) {
        int x0 = start + e8;
        int sjA = ssorted[x0 < end ? x0 : start];
        if (nst > 1) {
            int x1 = start + 8 + e8;
            sjB = ssorted[x1 < end ? x1 : start];
        }
        elA = el[sjA];
        fvA = f8[(size_t)sjA * 8 + li];
    }
    for (int js = 0; js < nst; ++js) {
        if (js + 1 < nst) {
            elB = el[sjB];
            fvB = f8[(size_t)sjB * 8 + li];
        }
        if (js + 2 < nst) {
            int x = start + (js + 2) * 8 + e8;
            sjN = ssorted[x < end ? x : start];
        }
        bool vld = (start + js * 8 + e8) < end;
        float ev = elA + ern;
        ev = ev > 0.f ? ev : NEG_SLOPE * ev;
        float w = vld ? __expf(ev) : 0.f;
        ws += w;
        #pragma unroll
        for (int i = 0; i < 8; ++i) acc[i] = fmaf(w, (float)fvA[i], acc[i]);
        elA = elB; fvA = fvB; sjB = sjN;
    }
    #pragma unroll
    for (int o = 8; o < 64; o <<= 1) {
        ws += __shfl_xor(ws, o);
        #pragma unroll
        for (int i = 0; i < 8; ++i) acc[i] += __shfl_xor(acc[i], o);
    }
    if (e8 == 0) {
        float inv = ws > 0.f ? 1.f / ws : 0.f;
        float4 o0, o1;
        o0.x = acc[0] * inv; o0.y = acc[1] * inv;
        o0.z = acc[2] * inv; o0.w = acc[3] * inv;
        o1.x = acc[4] * inv; o1.y = acc[5] * inv;
        o1.z = acc[6] * inv; o1.w = acc[7] * inv;
        float4* op = (float4*)(out + (size_t)n * 64 + li * 8);
        op[0] = o0; op[1] = o1;
    }
}

// ---------------- launch ----------------

extern "C" void kernel_launch(void* const* d_in, const int* in_sizes, int n_in,
                              void* d_out, int out_size, void* d_ws, size_t ws_size,
                              hipStream_t stream) {
    const float* x   = (const float*)d_in[0];
    const int*   src = (const int*)d_in[1];
    const int*   dst = (const int*)d_in[2];
    const float* W1  = (const float*)d_in[3];
    const float* al1 = (const float*)d_in[4];
    const float* ar1 = (const float*)d_in[5];
    const float* W2  = (const float*)d_in[6];
    const float* al2 = (const float*)d_in[7];
    const float* ar2 = (const float*)d_in[8];
    float* out = (float*)d_out;

    char* ws = (char*)d_ws;
    size_t off = 0;
    auto alloc = [&](size_t bytes) -> void* {
        void* p = ws + off;
        off += (bytes + 255) & ~(size_t)255;
        return p;
    };
    _Float16* feat1 = (_Float16*)alloc((size_t)NNODES * 256 * 2);   // node-major [N][256]
    _Float16* h1    = (_Float16*)alloc((size_t)NNODES * 256 * 2);   // node-major [N][256]
    _Float16* W1t   = (_Float16*)alloc((size_t)256 * 256 * 2);
    _Float16* W2t   = (_Float16*)alloc((size_t)64 * 256 * 2);
    float* el1    = (float*)alloc((size_t)NNODES * 4 * 4);          // node-major [N][4]
    float* er1    = (float*)alloc((size_t)NNODES * 4 * 4);
    float* el2    = (float*)alloc((size_t)NNODES * 4);
    float* er2    = (float*)alloc((size_t)NNODES * 4);
    int* deg      = (int*)alloc((size_t)NNODES * 4);
    int* cursor   = (int*)alloc((size_t)NNODES * 4);
    int* offs     = (int*)alloc((size_t)(NNODES + 1) * 4);
    int* bsums    = (int*)alloc((size_t)NB * 4);
    int* ssorted  = (int*)alloc((size_t)NEDGES * 4);
    _Float16* feat2 = feat1;   // feat1 dead after spmm1; reuse for layer 2
    _Float16* xh = h1;         // x-fp16 staging; dead before spmm1 writes h1

    // --- zero counters ---
    hipMemsetAsync(deg, 0, (size_t)NNODES * 4, stream);
    hipMemsetAsync(cursor, 0, (size_t)NNODES * 4, stream);

    // --- fused prep: hist + W->fp16 + x->fp16 (independent) ---
    prep_kernel<<<HB + XB + WB, 256, 0, stream>>>(dst, deg, W1, W1t, W2, W2t, x, xh);

    // --- CSR scan ---
    bsum_kernel<<<NB, 256, 0, stream>>>(deg, bsums);
    scan_write_kernel<<<NB, 256, 0, stream>>>(deg, bsums, offs);

    // --- fused gemm1 (feature chain) + scatter (CSR chain) ---
    int gemmBlocks = ((NNODES + 63) / 64) * 2;   // 1564
    gemm1_scatter_kernel<<<gemmBlocks + HB, 256, 0, stream>>>(
        xh, W1t, feat1, al1, ar1, el1, er1, gemmBlocks,
        src, dst, offs, cursor, ssorted);

    // --- Layer 1 aggregation ---
    spmm1_kernel<<<(NNODES + 3) / 4, 256, 0, stream>>>(
        feat1, el1, er1, offs, ssorted, h1);

    // --- Layer 2: BM=64 fp16 GEMM + fused el/er; depth-2 SpMM ---
    gemm_f16_kernel<64, 64, 2><<<dim3(1, (NNODES + 63) / 64), 256, 0, stream>>>(
        h1, W2t, feat2, al2, ar2, el2, er2, NNODES, 64);
    spmm2_kernel<<<(NNODES + 3) / 4, 256, 0, stream>>>(
        feat2, el2, er2, offs, ssorted, out);
}

// Round 15
// 300.981 us; speedup vs baseline: 1.1444x; 1.0516x over previous
//
#include <hip/hip_runtime.h>
#include <math.h>

#define NNODES 50000
#define NEDGES 800000
#define INDIM 256
#define HID 64
#define HEADS 4
#define OUTDIM 64
#define NEG_SLOPE 0.2f
#define NB ((NNODES + 1023) / 1024)   // 49 scan blocks
#define HB ((NEDGES + 255) / 256)     // 3125 hist blocks
#define XB ((NNODES * (INDIM / 8) + 255) / 256)   // 6250 convert_x blocks
#define WB ((256 * 256 + 256 * 64 + 255) / 256)   // 320 convert_wt blocks

typedef __attribute__((ext_vector_type(4))) float f32x4;
typedef _Float16 __attribute__((ext_vector_type(8))) half8;

// ---------------- CSR build (bsum/scan stay standalone) ----------------

__global__ __launch_bounds__(256) void bsum_kernel(const int* __restrict__ deg,
                                                   int* __restrict__ bsums) {
    int b = blockIdx.x, t = threadIdx.x;
    int base = b * 1024 + t * 4;
    int s = 0;
    #pragma unroll
    for (int e = 0; e < 4; ++e) { int i = base + e; if (i < NNODES) s += deg[i]; }
    #pragma unroll
    for (int o = 32; o; o >>= 1) s += __shfl_xor(s, o);
    __shared__ int ws[4];
    int lane = t & 63, wid = t >> 6;
    if (lane == 0) ws[wid] = s;
    __syncthreads();
    if (t == 0) bsums[b] = ws[0] + ws[1] + ws[2] + ws[3];
}

__global__ __launch_bounds__(256) void scan_write_kernel(const int* __restrict__ deg,
                                                         const int* __restrict__ bsums,
                                                         int* __restrict__ offs) {
    int b = blockIdx.x, t = threadIdx.x;
    int lane = t & 63, wid = t >> 6;
    int bv = (lane < b) ? bsums[lane] : 0;    // b <= NB-1 < 64
    #pragma unroll
    for (int o = 32; o; o >>= 1) bv += __shfl_xor(bv, o);  // block global offset
    int base = b * 1024 + t * 4;
    int v[4]; int tsum = 0;
    #pragma unroll
    for (int e = 0; e < 4; ++e) {
        int i = base + e;
        v[e] = (i < NNODES) ? deg[i] : 0;
        tsum += v[e];
    }
    int p = tsum;
    #pragma unroll
    for (int o = 1; o < 64; o <<= 1) { int u = __shfl_up(p, o); if (lane >= o) p += u; }
    __shared__ int ws[4];
    if (lane == 63) ws[wid] = p;
    __syncthreads();
    int woff = 0;
    for (int i = 0; i < wid; ++i) woff += ws[i];
    int run = bv + woff + p - tsum;           // exclusive prefix for this thread
    #pragma unroll
    for (int e = 0; e < 4; ++e) {
        int i = base + e;
        if (i < NNODES) { offs[i] = run; run += v[e]; }
    }
    if (b == 0 && t == 0) offs[NNODES] = NEDGES;
}

// ---------------- fused prep: hist(+rank) + convert_wt + convert_x --------
// R26: hist's atomicAdd return value IS the edge's within-bucket rank —
// store it so the scatter pass needs no atomics (R25 post-mortem: fused
// scatter inherited gemm's VGPR-52 -> occ 36% -> atomic serialization).

__global__ __launch_bounds__(256) void prep_kernel(const int* __restrict__ dst,
                                                   int* __restrict__ deg,
                                                   int* __restrict__ rank,
                                                   const float* __restrict__ W1,
                                                   _Float16* __restrict__ W1t,
                                                   const float* __restrict__ W2,
                                                   _Float16* __restrict__ W2t,
                                                   const float* __restrict__ x,
                                                   _Float16* __restrict__ xh) {
    int b = blockIdx.x;
    if (b < HB) {                         // histogram + rank capture
        int i = b * 256 + threadIdx.x;
        if (i < NEDGES) rank[i] = atomicAdd(&deg[dst[i]], 1);
    } else if (b < HB + XB) {             // x -> fp16 (one half8/thread)
        int i = (b - HB) * 256 + threadIdx.x;
        if (i < NNODES * (INDIM / 8)) {
            const float4* xp = (const float4*)x;
            float4 f0 = xp[(size_t)i * 2];
            float4 f1 = xp[(size_t)i * 2 + 1];
            half8 v;
            v[0] = (_Float16)f0.x; v[1] = (_Float16)f0.y;
            v[2] = (_Float16)f0.z; v[3] = (_Float16)f0.w;
            v[4] = (_Float16)f1.x; v[5] = (_Float16)f1.y;
            v[6] = (_Float16)f1.z; v[7] = (_Float16)f1.w;
            ((half8*)xh)[i] = v;
        }
    } else {                              // weight transpose -> fp16
        int idx = (b - HB - XB) * 256 + threadIdx.x;
        if (idx < 256 * 256) {
            int k = idx >> 8, n = idx & 255;
            W1t[n * 256 + k] = (_Float16)W1[idx];
        } else if (idx < 256 * 256 + 256 * 64) {
            int j = idx - 256 * 256;
            int k = j >> 6, n = j & 63;
            W2t[n * 256 + k] = (_Float16)W2[j];
        }
    }
}

// ---------------- fp16 MFMA GEMM body (shared by fused + standalone) -----
// ELR=1 (BN=128): el/er NODE-MAJOR [M][4] for spmm1's one-line el gather.
// ELR=2 (BN=64): single head; per-wn partial dot + LDS combine.

template <int BM, int BN, int ELR>
__device__ __forceinline__ void gemm_body(
        const _Float16* __restrict__ Ah,
        const _Float16* __restrict__ Bt,
        _Float16* __restrict__ C,
        const float* __restrict__ al, const float* __restrict__ ar,
        float* __restrict__ el, float* __restrict__ er,
        int M, int N, int m0, int n0) {
    constexpr int K = 256;
    constexpr int NT = BN / 32;       // 16-wide n-tiles per wave
    constexpr int TM = BM / 32;       // 16-row tiles per wave
    int t = threadIdx.x;
    int lane = t & 63, w = t >> 6;
    int wm = w >> 1, wn = w & 1;
    int lr = lane & 15, quad = lane >> 4;

    f32x4 acc[TM][NT];
    #pragma unroll
    for (int i = 0; i < TM; ++i)
        #pragma unroll
        for (int j = 0; j < NT; ++j) acc[i][j] = (f32x4){0.f, 0.f, 0.f, 0.f};

    int arow[TM];
    #pragma unroll
    for (int i = 0; i < TM; ++i) {
        int r = m0 + wm * (BM / 2) + i * 16 + lr;
        arow[i] = (r < M) ? r : (M - 1);
    }
    int brow[NT];
    #pragma unroll
    for (int j = 0; j < NT; ++j) brow[j] = n0 + wn * NT * 16 + j * 16 + lr;

    #pragma unroll
    for (int kk = 0; kk < K; kk += 32) {
        half8 a[TM], b[NT];
        #pragma unroll
        for (int i = 0; i < TM; ++i)
            a[i] = *(const half8*)(Ah + (size_t)arow[i] * K + kk + quad * 8);
        #pragma unroll
        for (int j = 0; j < NT; ++j)
            b[j] = *(const half8*)(Bt + (size_t)brow[j] * K + kk + quad * 8);
        #pragma unroll
        for (int i = 0; i < TM; ++i)
            #pragma unroll
            for (int j = 0; j < NT; ++j)
                acc[i][j] = __builtin_amdgcn_mfma_f32_16x16x32_f16(a[i], b[j], acc[i][j], 0, 0, 0);
    }
    #pragma unroll
    for (int i = 0; i < TM; ++i) {
        #pragma unroll
        for (int r = 0; r < 4; ++r) {
            int row = m0 + wm * (BM / 2) + i * 16 + quad * 4 + r;
            if (row < M) {
                #pragma unroll
                for (int j = 0; j < NT; ++j)
                    C[(size_t)row * N + n0 + wn * NT * 16 + j * 16 + lr] =
                        (_Float16)acc[i][j][r];
            }
        }
    }
    if constexpr (ELR == 1) {
        int h = n0 / 64 + wn;
        float alh[NT], arh[NT];
        #pragma unroll
        for (int j = 0; j < NT; ++j) {
            alh[j] = al[h * 64 + j * 16 + lr];
            arh[j] = ar[h * 64 + j * 16 + lr];
        }
        #pragma unroll
        for (int i = 0; i < TM; ++i) {
            #pragma unroll
            for (int r = 0; r < 4; ++r) {
                float pel = 0.f, per = 0.f;
                #pragma unroll
                for (int j = 0; j < NT; ++j) {
                    pel = fmaf(acc[i][j][r], alh[j], pel);
                    per = fmaf(acc[i][j][r], arh[j], per);
                }
                #pragma unroll
                for (int o = 1; o < 16; o <<= 1) {
                    pel += __shfl_xor(pel, o);
                    per += __shfl_xor(per, o);
                }
                if (lr == 0) {
                    int row = m0 + wm * (BM / 2) + i * 16 + quad * 4 + r;
                    if (row < M) {
                        el[(size_t)row * 4 + h] = pel;   // node-major [M][4]
                        er[(size_t)row * 4 + h] = per;
                    }
                }
            }
        }
    }
    if constexpr (ELR == 2) {
        __shared__ float elbuf[BM], erbuf[BM];
        float alv[NT], arv[NT];
        #pragma unroll
        for (int j = 0; j < NT; ++j) {
            alv[j] = al[wn * NT * 16 + j * 16 + lr];
            arv[j] = ar[wn * NT * 16 + j * 16 + lr];
        }
        float pel_s[TM][4], per_s[TM][4];
        #pragma unroll
        for (int i = 0; i < TM; ++i) {
            #pragma unroll
            for (int r = 0; r < 4; ++r) {
                float pel = 0.f, per = 0.f;
                #pragma unroll
                for (int j = 0; j < NT; ++j) {
                    pel = fmaf(acc[i][j][r], alv[j], pel);
                    per = fmaf(acc[i][j][r], arv[j], per);
                }
                #pragma unroll
                for (int o = 1; o < 16; o <<= 1) {
                    pel += __shfl_xor(pel, o);
                    per += __shfl_xor(per, o);
                }
                pel_s[i][r] = pel; per_s[i][r] = per;
            }
        }
        if (wn == 1 && lr == 0) {
            #pragma unroll
            for (int i = 0; i < TM; ++i)
                #pragma unroll
                for (int r = 0; r < 4; ++r) {
                    int rl = wm * (BM / 2) + i * 16 + quad * 4 + r;
                    elbuf[rl] = pel_s[i][r];
                    erbuf[rl] = per_s[i][r];
                }
        }
        __syncthreads();
        if (wn == 0 && lr == 0) {
            #pragma unroll
            for (int i = 0; i < TM; ++i)
                #pragma unroll
                for (int r = 0; r < 4; ++r) {
                    int rl = wm * (BM / 2) + i * 16 + quad * 4 + r;
                    int row = m0 + rl;
                    if (row < M) {
                        el[row] = pel_s[i][r] + elbuf[rl];
                        er[row] = per_s[i][r] + erbuf[rl];
                    }
                }
        }
    }
}

// ---------------- fused gemm1 + atomic-free scatter -----------------------
// R26: scatter = ssorted[offs[d] + rank[i]] = src[i]; no atomics, pure
// latency-tolerant loads/stores -> coexists with gemm's VGPR-52 alloc.

__global__ __launch_bounds__(256) void gemm1_scatter_kernel(
        const _Float16* __restrict__ Ah, const _Float16* __restrict__ Bt,
        _Float16* __restrict__ C,
        const float* __restrict__ al, const float* __restrict__ ar,
        float* __restrict__ el, float* __restrict__ er,
        int gemmBlocks,
        const int* __restrict__ src, const int* __restrict__ dst,
        const int* __restrict__ rank,
        const int* __restrict__ offs,
        int* __restrict__ ssorted) {
    int b = blockIdx.x;
    if (b < gemmBlocks) {
        int m0 = (b >> 1) * 64, n0 = (b & 1) * 128;
        gemm_body<64, 128, 1>(Ah, Bt, C, al, ar, el, er, NNODES, 256, m0, n0);
    } else {
        int i = (b - gemmBlocks) * 256 + threadIdx.x;
        if (i < NEDGES) {
            int d = dst[i];
            ssorted[offs[d] + rank[i]] = src[i];
        }
    }
}

// ---------------- standalone gemm (layer 2) ------------------------------

template <int BM, int BN, int ELR>
__global__ __launch_bounds__(256) void gemm_f16_kernel(
        const _Float16* __restrict__ Ah, const _Float16* __restrict__ Bt,
        _Float16* __restrict__ C,
        const float* __restrict__ al, const float* __restrict__ ar,
        float* __restrict__ el, float* __restrict__ er,
        int M, int N) {
    int m0 = blockIdx.y * BM, n0 = blockIdx.x * BN;
    gemm_body<BM, BN, ELR>(Ah, Bt, C, al, ar, el, er, M, N, m0, n0);
}

// ---------------- fused softmax + weighted aggregation (layer 1) ----------
// R22 winner: depth-2 software pipeline; wave = node, all 4 heads; 2 edges
// per VMEM; consume slot j while slot j+1's el/feat and slot j+2's ssorted
// are in flight. 24 VGPR, occ 66%. R24 verdict: 63.5us is the L2-miss
// random-service floor (~3.6 TB/s) - deeper pipelining is null.

__global__ __launch_bounds__(256) void spmm1_kernel(const _Float16* __restrict__ feat,  // [N][256]
                                                    const float* __restrict__ el,  // [N][4]
                                                    const float* __restrict__ er,  // [N][4]
                                                    const int* __restrict__ offs,
                                                    const int* __restrict__ ssorted,
                                                    _Float16* __restrict__ h1) {
    int n = blockIdx.x * 4 + (threadIdx.x >> 6);   // wave = node, all 4 heads
    if (n >= NNODES) return;
    int l = threadIdx.x & 63;
    int p2 = l >> 5;              // edge-pair half (2 edges per VMEM)
    int q  = l & 31;              // 32 lanes cover 512B = 4 heads x 64 dims
    int h  = q >> 3;              // this lane's head
    int start = offs[n], end = offs[n + 1];
    int nst = (end - start + 1) >> 1;   // 2-edge slots
    float ern = er[(size_t)n * 4 + h];
    const half8* f8 = (const half8*)feat;   // node stride 32 half8
    float acc[8];
    #pragma unroll
    for (int i = 0; i < 8; ++i) acc[i] = 0.f;
    float ws = 0.f;
    half8 z;
    #pragma unroll
    for (int i = 0; i < 8; ++i) z[i] = (_Float16)0;
    int sjB = 0, sjN = 0;
    float elA = 0.f, elB = 0.f;
    half8 fvA = z, fvB = z;
    if (nst > 0) {                 // prologue: slot0 chain + slot1 sj in flight
        int x0 = start + p2;
        int sjA = ssorted[x0 < end ? x0 : start];
        if (nst > 1) {
            int x1 = start + 2 + p2;
            sjB = ssorted[x1 < end ? x1 : start];
        }
        elA = el[(size_t)sjA * 4 + h];
        fvA = f8[(size_t)sjA * 32 + q];
    }
    for (int js = 0; js < nst; ++js) {
        if (js + 1 < nst) {        // issue next slot's el/feat (sj ready)
            elB = el[(size_t)sjB * 4 + h];
            fvB = f8[(size_t)sjB * 32 + q];
        }
        if (js + 2 < nst) {        // issue next-next slot's sj
            int x = start + (js + 2) * 2 + p2;
            sjN = ssorted[x < end ? x : start];
        }
        // consume slot js (A regs; waits only on loads issued last iteration)
        bool vld = (start + js * 2 + p2) < end;
        float ev = elA + ern;
        ev = ev > 0.f ? ev : NEG_SLOPE * ev;
        float w = vld ? __expf(ev) : 0.f;    // no max-sub (safe: |e|<~8)
        ws += w;
        #pragma unroll
        for (int i = 0; i < 8; ++i) acc[i] = fmaf(w, (float)fvA[i], acc[i]);
        elA = elB; fvA = fvB; sjB = sjN;     // rotate
    }
    // fold the two edge-pair halves
    ws += __shfl_xor(ws, 32);
    #pragma unroll
    for (int i = 0; i < 8; ++i) acc[i] += __shfl_xor(acc[i], 32);
    if (l < 32) {
        float inv = ws > 0.f ? 1.f / ws : 0.f;
        half8 hv;
        #pragma unroll
        for (int i = 0; i < 8; ++i) {
            float v = acc[i] * inv;
            v = v > 0.f ? v : __expf(v) - 1.f;   // ELU
            hv[i] = (_Float16)v;
        }
        *(half8*)&h1[(size_t)n * 256 + q * 8] = hv;    // 512B/node contiguous
    }
}

// ---------------- fused softmax + weighted aggregation (layer 2) ----------
// Single head, 64 dims, fp32 out. Depth-2 rotation (slots of 8 edges).

__global__ __launch_bounds__(256) void spmm2_kernel(const _Float16* __restrict__ feat,
                                                    const float* __restrict__ el,
                                                    const float* __restrict__ er,
                                                    const int* __restrict__ offs,
                                                    const int* __restrict__ ssorted,
                                                    float* __restrict__ out) {
    int n = blockIdx.x * 4 + (threadIdx.x >> 6);
    if (n >= NNODES) return;
    int l = threadIdx.x & 63;
    int e8 = l >> 3, li = l & 7;
    int start = offs[n], end = offs[n + 1];
    int nst = (end - start + 7) >> 3;   // 8-edge slots
    float ern = er[n];
    const half8* f8 = (const half8*)feat;   // node stride 8 half8s
    float acc[8];
    #pragma unroll
    for (int i = 0; i < 8; ++i) acc[i] = 0.f;
    float ws = 0.f;
    half8 z;
    #pragma unroll
    for (int i = 0; i < 8; ++i) z[i] = (_Float16)0;
    int sjB = 0, sjN = 0;
    float elA = 0.f, elB = 0.f;
    half8 fvA = z, fvB = z;
    if (nst > 0) {
        int x0 = start + e8;
        int sjA = ssorted[x0 < end ? x0 : start];
        if (nst > 1) {
            int x1 = start + 8 + e8;
            sjB = ssorted[x1 < end ? x1 : start];
        }
        elA = el[sjA];
        fvA = f8[(size_t)sjA * 8 + li];
    }
    for (int js = 0; js < nst; ++js) {
        if (js + 1 < nst) {
            elB = el[sjB];
            fvB = f8[(size_t)sjB * 8 + li];
        }
        if (js + 2 < nst) {
            int x = start + (js + 2) * 8 + e8;
            sjN = ssorted[x < end ? x : start];
        }
        bool vld = (start + js * 8 + e8) < end;
        float ev = elA + ern;
        ev = ev > 0.f ? ev : NEG_SLOPE * ev;
        float w = vld ? __expf(ev) : 0.f;
        ws += w;
        #pragma unroll
        for (int i = 0; i < 8; ++i) acc[i] = fmaf(w, (float)fvA[i], acc[i]);
        elA = elB; fvA = fvB; sjB = sjN;
    }
    #pragma unroll
    for (int o = 8; o < 64; o <<= 1) {
        ws += __shfl_xor(ws, o);
        #pragma unroll
        for (int i = 0; i < 8; ++i) acc[i] += __shfl_xor(acc[i], o);
    }
    if (e8 == 0) {
        float inv = ws > 0.f ? 1.f / ws : 0.f;
        float4 o0, o1;
        o0.x = acc[0] * inv; o0.y = acc[1] * inv;
        o0.z = acc[2] * inv; o0.w = acc[3] * inv;
        o1.x = acc[4] * inv; o1.y = acc[5] * inv;
        o1.z = acc[6] * inv; o1.w = acc[7] * inv;
        float4* op = (float4*)(out + (size_t)n * 64 + li * 8);
        op[0] = o0; op[1] = o1;
    }
}

// ---------------- launch ----------------

extern "C" void kernel_launch(void* const* d_in, const int* in_sizes, int n_in,
                              void* d_out, int out_size, void* d_ws, size_t ws_size,
                              hipStream_t stream) {
    const float* x   = (const float*)d_in[0];
    const int*   src = (const int*)d_in[1];
    const int*   dst = (const int*)d_in[2];
    const float* W1  = (const float*)d_in[3];
    const float* al1 = (const float*)d_in[4];
    const float* ar1 = (const float*)d_in[5];
    const float* W2  = (const float*)d_in[6];
    const float* al2 = (const float*)d_in[7];
    const float* ar2 = (const float*)d_in[8];
    float* out = (float*)d_out;

    char* ws = (char*)d_ws;
    size_t off = 0;
    auto alloc = [&](size_t bytes) -> void* {
        void* p = ws + off;
        off += (bytes + 255) & ~(size_t)255;
        return p;
    };
    _Float16* feat1 = (_Float16*)alloc((size_t)NNODES * 256 * 2);   // node-major [N][256]
    _Float16* h1    = (_Float16*)alloc((size_t)NNODES * 256 * 2);   // node-major [N][256]
    _Float16* W1t   = (_Float16*)alloc((size_t)256 * 256 * 2);
    _Float16* W2t   = (_Float16*)alloc((size_t)64 * 256 * 2);
    float* el1    = (float*)alloc((size_t)NNODES * 4 * 4);          // node-major [N][4]
    float* er1    = (float*)alloc((size_t)NNODES * 4 * 4);
    float* el2    = (float*)alloc((size_t)NNODES * 4);
    float* er2    = (float*)alloc((size_t)NNODES * 4);
    int* deg      = (int*)alloc((size_t)NNODES * 4);
    int* rank     = (int*)alloc((size_t)NEDGES * 4);                // 3.2 MB
    int* offs     = (int*)alloc((size_t)(NNODES + 1) * 4);
    int* bsums    = (int*)alloc((size_t)NB * 4);
    int* ssorted  = (int*)alloc((size_t)NEDGES * 4);
    _Float16* feat2 = feat1;   // feat1 dead after spmm1; reuse for layer 2
    _Float16* xh = h1;         // x-fp16 staging; dead before spmm1 writes h1

    // --- zero degree counters ---
    hipMemsetAsync(deg, 0, (size_t)NNODES * 4, stream);

    // --- fused prep: hist(+rank) + W->fp16 + x->fp16 (independent) ---
    prep_kernel<<<HB + XB + WB, 256, 0, stream>>>(dst, deg, rank, W1, W1t, W2, W2t, x, xh);

    // --- CSR scan ---
    bsum_kernel<<<NB, 256, 0, stream>>>(deg, bsums);
    scan_write_kernel<<<NB, 256, 0, stream>>>(deg, bsums, offs);

    // --- fused gemm1 (feature chain) + atomic-free scatter (CSR chain) ---
    int gemmBlocks = ((NNODES + 63) / 64) * 2;   // 1564
    gemm1_scatter_kernel<<<gemmBlocks + HB, 256, 0, stream>>>(
        xh, W1t, feat1, al1, ar1, el1, er1, gemmBlocks,
        src, dst, rank, offs, ssorted);

    // --- Layer 1 aggregation ---
    spmm1_kernel<<<(NNODES + 3) / 4, 256, 0, stream>>>(
        feat1, el1, er1, offs, ssorted, h1);

    // --- Layer 2: BM=64 fp16 GEMM + fused el/er; depth-2 SpMM ---
    gemm_f16_kernel<64, 64, 2><<<dim3(1, (NNODES + 63) / 64), 256, 0, stream>>>(
        h1, W2t, feat2, al2, ar2, el2, er2, NNODES, 64);
    spmm2_kernel<<<(NNODES + 3) / 4, 256, 0, stream>>>(
        feat2, el2, er2, offs, ssorted, out);
}